// Round 2
// baseline (4215.071 us; speedup 1.0000x reference)
//
#include <hip/hip_runtime.h>
#include <cmath>
#include <cfloat>

#define DIM   2048
#define SEQ   4096
#define NH    16
#define NKV   4
#define HD    128
#define KVD   512   // NKV*HD

// ---------------------------------------------------------------------------
// GEMM: C[M,N] = A[M,K] * B[N,K]^T   (all row-major, fp32)
// 128x128 tile, BK=32, 256 threads, 8x8 micro-tile per thread.
// LDS tiles stored k-major (transposed) so the inner loop reads are
// contiguous float4s (conflict-free); the transpose cost is paid on the
// (rare) staging writes.
// ---------------------------------------------------------------------------
__device__ __forceinline__ void gemm_tile_128(const float* __restrict__ A,
                                              const float* __restrict__ B,
                                              float* __restrict__ C,
                                              int bm, int bn, int N, int K) {
    __shared__ float As[32][128];   // [k][m]
    __shared__ float Bs[32][128];   // [k][n]
    const int tid = threadIdx.x;
    const int tx  = tid & 15;       // -> 8 cols
    const int ty  = tid >> 4;       // -> 8 rows
    float acc[8][8] = {};

    for (int k0 = 0; k0 < K; k0 += 32) {
#pragma unroll
        for (int it = 0; it < 4; ++it) {
            int idx = tid + it * 256;
            int r   = idx >> 3;          // 0..127 (tile row)
            int kq  = (idx & 7) << 2;    // 0,4,...,28
            float4 a4 = *(const float4*)&A[(size_t)(bm + r) * K + k0 + kq];
            As[kq + 0][r] = a4.x; As[kq + 1][r] = a4.y;
            As[kq + 2][r] = a4.z; As[kq + 3][r] = a4.w;
            float4 b4 = *(const float4*)&B[(size_t)(bn + r) * K + k0 + kq];
            Bs[kq + 0][r] = b4.x; Bs[kq + 1][r] = b4.y;
            Bs[kq + 2][r] = b4.z; Bs[kq + 3][r] = b4.w;
        }
        __syncthreads();
#pragma unroll
        for (int kk = 0; kk < 32; ++kk) {
            float4 a0 = *(const float4*)&As[kk][ty * 8];
            float4 a1 = *(const float4*)&As[kk][ty * 8 + 4];
            float4 b0 = *(const float4*)&Bs[kk][tx * 8];
            float4 b1 = *(const float4*)&Bs[kk][tx * 8 + 4];
            float av[8] = {a0.x, a0.y, a0.z, a0.w, a1.x, a1.y, a1.z, a1.w};
            float bv[8] = {b0.x, b0.y, b0.z, b0.w, b1.x, b1.y, b1.z, b1.w};
#pragma unroll
            for (int i = 0; i < 8; ++i)
#pragma unroll
                for (int j = 0; j < 8; ++j)
                    acc[i][j] = fmaf(av[i], bv[j], acc[i][j]);
        }
        __syncthreads();
    }
#pragma unroll
    for (int i = 0; i < 8; ++i) {
        float4 o0 = {acc[i][0], acc[i][1], acc[i][2], acc[i][3]};
        float4 o1 = {acc[i][4], acc[i][5], acc[i][6], acc[i][7]};
        size_t row = (size_t)(bm + ty * 8 + i) * N + bn + tx * 8;
        *(float4*)&C[row]     = o0;
        *(float4*)&C[row + 4] = o1;
    }
}

__global__ __launch_bounds__(256) void k_gemm_q(const float* __restrict__ x,
                                                const float* __restrict__ Wq,
                                                float* __restrict__ q) {
    gemm_tile_128(x, Wq, q, blockIdx.y * 128, blockIdx.x * 128, DIM, DIM);
}

// K and V projections fused into one launch (fills more CUs than two
// 128-block launches back to back).
__global__ __launch_bounds__(256) void k_gemm_kv(const float* __restrict__ x,
                                                 const float* __restrict__ Wk,
                                                 const float* __restrict__ Wv,
                                                 float* __restrict__ k,
                                                 float* __restrict__ v) {
    const int nb = blockIdx.x;               // 0..7
    const float* B = (nb < 4) ? Wk : Wv;
    float*       C = (nb < 4) ? k  : v;
    const int bn = (nb & 3) * 128;
    gemm_tile_128(x, B, C, blockIdx.y * 128, bn, KVD, DIM);
}

__global__ __launch_bounds__(256) void k_gemm_o(const float* __restrict__ a,
                                                const float* __restrict__ Wo,
                                                float* __restrict__ out) {
    gemm_tile_128(a, Wo, out, blockIdx.y * 128, blockIdx.x * 128, DIM, DIM);
}

// ---------------------------------------------------------------------------
// Per-(token, head) RMSNorm + RoPE (+ q_gain for Q heads), in place.
// grid = (SEQ, NH+NKV), block = 128 (one lane per channel of the head).
// RoPE follows the reference exactly:
//   first  = x1*cos + x2*sin
//   second = -x1*sin + x2*cos
// angle computed in double to stay within ~1 ulp of the true value.
// ---------------------------------------------------------------------------
__global__ __launch_bounds__(128) void k_norm_rope(float* __restrict__ q,
                                                   float* __restrict__ k,
                                                   const float* __restrict__ qg) {
    const int t    = blockIdx.x;
    const int head = blockIdx.y;
    const int d    = threadIdx.x;

    float* base;
    float  gain = 1.0f;
    if (head < NH) {
        base = q + (size_t)t * DIM + head * HD;
        gain = qg[head];
    } else {
        base = k + (size_t)t * KVD + (head - NH) * HD;
    }

    float xv = base[d];
    float ss = xv * xv;
#pragma unroll
    for (int m = 1; m <= 32; m <<= 1) ss += __shfl_xor(ss, m, 64);

    __shared__ float red[2];
    __shared__ float sh[128];
    if ((d & 63) == 0) red[d >> 6] = ss;
    __syncthreads();
    float ms  = (red[0] + red[1]) * (1.0f / 128.0f);
    float inv = 1.0f / sqrtf(ms + 1.1920928955078125e-07f);  // finfo(f32).eps
    sh[d] = xv * inv;
    __syncthreads();

    const int i = d & 63;
    double invf = pow(10000.0, -(double)i / 64.0);   // 10000^(-2i/128)
    double ang  = (double)t * invf;
    float  cs   = (float)cos(ang);
    float  sn   = (float)sin(ang);
    float  x1   = sh[i];
    float  x2   = sh[i + 64];
    float  outv = (d < 64) ? (x1 * cs + x2 * sn) : (x2 * cs - x1 * sn);
    base[d] = outv * gain;
}

// ---------------------------------------------------------------------------
// Causal GQA flash attention, fp32.
// grid = (SEQ/64, NH), block = 256 (tx = tid&15 -> cols, ty = tid>>4 -> rows).
// BQ=64 query rows per block, BK=32 kv rows per tile.
// LDS (64 KB total, 2 blocks/CU):
//   Qs[128][64]  Q transposed [d][r]      32 KB  (staged once)
//   KPs          union: Ks [d][c] 128x32  16 KB  / Ps [r][kk] 64x(stride36)
//   Vs[32][128]                           16 KB
// Per tile: stage K,V -> S=QK^T (4x2 micro) -> online softmax (16-lane
// shuffle row reduce) -> P to LDS -> PV (4x8 micro) -> O accum.
// ---------------------------------------------------------------------------
__global__ __launch_bounds__(256) void k_attn(const float* __restrict__ q,
                                              const float* __restrict__ k,
                                              const float* __restrict__ v,
                                              float* __restrict__ o) {
    __shared__ float Qs[128][64];
    __shared__ float KPs[4096];     // Ks: [d*32+c] ; later Ps: [r*36+kk]
    __shared__ float Vs[32][128];

    const int tid = threadIdx.x;
    const int tx  = tid & 15;
    const int ty  = tid >> 4;
    const int qb  = gridDim.x - 1 - blockIdx.x;  // long blocks launch first
    const int h   = blockIdx.y;
    const int kvh = h >> 2;                      // GQA group of 4
    const int q0  = qb * 64;

    // stage Q transposed (coalesced global, conflicted LDS write - once)
#pragma unroll
    for (int it = 0; it < 8; ++it) {
        int idx = tid + it * 256;
        int d4  = (idx & 31) << 2;
        int r   = idx >> 5;                      // 0..63
        float4 a4 = *(const float4*)&q[(size_t)(q0 + r) * DIM + h * HD + d4];
        Qs[d4 + 0][r] = a4.x; Qs[d4 + 1][r] = a4.y;
        Qs[d4 + 2][r] = a4.z; Qs[d4 + 3][r] = a4.w;
    }

    float oacc[4][8] = {};
    float mrow[4], lrow[4];
#pragma unroll
    for (int i = 0; i < 4; ++i) { mrow[i] = -FLT_MAX; lrow[i] = 0.0f; }
    const float scale = 0.08838834764831845f;    // 128^-0.5

    const int ntiles = q0 / 32 + 2;
    for (int tile = 0; tile < ntiles; ++tile) {
        const int kv0 = tile * 32;
        __syncthreads();   // previous iter's readers of KPs/Vs are done
#pragma unroll
        for (int it = 0; it < 4; ++it) {
            int idx = tid + it * 256;
            int d4  = (idx & 31) << 2;
            int r   = idx >> 5;                  // 0..31
            float4 k4 = *(const float4*)&k[(size_t)(kv0 + r) * KVD + kvh * HD + d4];
            KPs[(d4 + 0) * 32 + r] = k4.x; KPs[(d4 + 1) * 32 + r] = k4.y;
            KPs[(d4 + 2) * 32 + r] = k4.z; KPs[(d4 + 3) * 32 + r] = k4.w;
            float4 v4 = *(const float4*)&v[(size_t)(kv0 + r) * KVD + kvh * HD + d4];
            *(float4*)&Vs[r][d4] = v4;
        }
        __syncthreads();

        // S = Q K^T  : rows ty*4..+3, cols tx*2..+1
        float sv0[4] = {}, sv1[4] = {};
        for (int d = 0; d < 128; ++d) {
            float4 a = *(const float4*)&Qs[d][ty * 4];
            float2 b = *(const float2*)&KPs[d * 32 + tx * 2];
            sv0[0] = fmaf(a.x, b.x, sv0[0]); sv1[0] = fmaf(a.x, b.y, sv1[0]);
            sv0[1] = fmaf(a.y, b.x, sv0[1]); sv1[1] = fmaf(a.y, b.y, sv1[1]);
            sv0[2] = fmaf(a.z, b.x, sv0[2]); sv1[2] = fmaf(a.z, b.y, sv1[2]);
            sv0[3] = fmaf(a.w, b.x, sv0[3]); sv1[3] = fmaf(a.w, b.y, sv1[3]);
        }
        __syncthreads();   // all Ks reads done; KPs becomes Ps

        // online softmax (row groups = 16 consecutive lanes, tx)
        float alpha[4];
#pragma unroll
        for (int i = 0; i < 4; ++i) {
            int row = q0 + ty * 4 + i;
            float s0 = sv0[i] * scale;
            float s1 = sv1[i] * scale;
            if (kv0 + tx * 2 + 0 > row) s0 = -FLT_MAX;
            if (kv0 + tx * 2 + 1 > row) s1 = -FLT_MAX;
            float rm = fmaxf(s0, s1);
#pragma unroll
            for (int mm = 1; mm <= 8; mm <<= 1) rm = fmaxf(rm, __shfl_xor(rm, mm, 64));
            float mnew = fmaxf(mrow[i], rm);
            float p0 = __expf(s0 - mnew);
            float p1 = __expf(s1 - mnew);
            float rs = p0 + p1;
#pragma unroll
            for (int mm = 1; mm <= 8; mm <<= 1) rs += __shfl_xor(rs, mm, 64);
            float al = __expf(mrow[i] - mnew);
            mrow[i]  = mnew;
            lrow[i]  = lrow[i] * al + rs;
            alpha[i] = al;
            KPs[(ty * 4 + i) * 36 + tx * 2 + 0] = p0;
            KPs[(ty * 4 + i) * 36 + tx * 2 + 1] = p1;
        }
#pragma unroll
        for (int i = 0; i < 4; ++i)
#pragma unroll
            for (int j = 0; j < 8; ++j) oacc[i][j] *= alpha[i];
        __syncthreads();   // Ps visible

        // PV: oacc[i][j] += sum_kk P[r][kk] * V[kk][tx*8+j]
#pragma unroll
        for (int k4 = 0; k4 < 8; ++k4) {
            float pk[4][4];
#pragma unroll
            for (int i = 0; i < 4; ++i) {
                float4 p4 = *(const float4*)&KPs[(ty * 4 + i) * 36 + k4 * 4];
                pk[i][0] = p4.x; pk[i][1] = p4.y; pk[i][2] = p4.z; pk[i][3] = p4.w;
            }
#pragma unroll
            for (int kk = 0; kk < 4; ++kk) {
                float4 v0 = *(const float4*)&Vs[k4 * 4 + kk][tx * 8];
                float4 v1 = *(const float4*)&Vs[k4 * 4 + kk][tx * 8 + 4];
#pragma unroll
                for (int i = 0; i < 4; ++i) {
                    float p = pk[i][kk];
                    oacc[i][0] = fmaf(p, v0.x, oacc[i][0]);
                    oacc[i][1] = fmaf(p, v0.y, oacc[i][1]);
                    oacc[i][2] = fmaf(p, v0.z, oacc[i][2]);
                    oacc[i][3] = fmaf(p, v0.w, oacc[i][3]);
                    oacc[i][4] = fmaf(p, v1.x, oacc[i][4]);
                    oacc[i][5] = fmaf(p, v1.y, oacc[i][5]);
                    oacc[i][6] = fmaf(p, v1.z, oacc[i][6]);
                    oacc[i][7] = fmaf(p, v1.w, oacc[i][7]);
                }
            }
        }
    }

    // epilogue: O /= l, write [T, H*HD]
#pragma unroll
    for (int i = 0; i < 4; ++i) {
        float invl = 1.0f / lrow[i];
        size_t row = (size_t)(q0 + ty * 4 + i) * DIM + h * HD + tx * 8;
        float4 r0 = {oacc[i][0] * invl, oacc[i][1] * invl,
                     oacc[i][2] * invl, oacc[i][3] * invl};
        float4 r1 = {oacc[i][4] * invl, oacc[i][5] * invl,
                     oacc[i][6] * invl, oacc[i][7] * invl};
        *(float4*)&o[row]     = r0;
        *(float4*)&o[row + 4] = r1;
    }
}

// ---------------------------------------------------------------------------
// Workspace budget (defensive: only 48 MB of d_ws used):
//   kbuf 8 MB | vbuf 8 MB | ao 32 MB.
// The Q projection lives in d_out (SEQ*DIM fp32 = 32 MB) until the attention
// kernel has consumed it; the out-projection then overwrites d_out.
// ---------------------------------------------------------------------------
extern "C" void kernel_launch(void* const* d_in, const int* in_sizes, int n_in,
                              void* d_out, int out_size, void* d_ws, size_t ws_size,
                              hipStream_t stream) {
    const float* x  = (const float*)d_in[0];
    const float* Wq = (const float*)d_in[1];
    const float* Wk = (const float*)d_in[2];
    const float* Wv = (const float*)d_in[3];
    const float* Wo = (const float*)d_in[4];
    const float* qg = (const float*)d_in[5];
    float* out = (float*)d_out;

    float* q    = out;                           // borrow d_out for Q (32 MB)
    float* kbuf = (float*)d_ws;                  // 8 MB
    float* vbuf = kbuf + (size_t)SEQ * KVD;      // 8 MB
    float* ao   = vbuf + (size_t)SEQ * KVD;      // 32 MB

    k_gemm_q <<<dim3(DIM / 128, SEQ / 128),       256, 0, stream>>>(x, Wq, q);
    k_gemm_kv<<<dim3(2 * KVD / 128, SEQ / 128),   256, 0, stream>>>(x, Wk, Wv, kbuf, vbuf);
    k_norm_rope<<<dim3(SEQ, NH + NKV),            128, 0, stream>>>(q, kbuf, qg);
    k_attn   <<<dim3(SEQ / 64, NH),               256, 0, stream>>>(q, kbuf, vbuf, ao);
    k_gemm_o <<<dim3(DIM / 128, SEQ / 128),       256, 0, stream>>>(ao, Wo, out);
}

// Round 3
// 1875.731 us; speedup vs baseline: 2.2472x; 2.2472x over previous
//
#include <hip/hip_runtime.h>
#include <hip/hip_bf16.h>
#include <cmath>
#include <cfloat>

#define DIM   2048
#define SEQ   4096
#define NH    16
#define NKV   4
#define HD    128
#define KVD   512   // NKV*HD

typedef __bf16 bf16x8 __attribute__((ext_vector_type(8)));
typedef float  f32x4  __attribute__((ext_vector_type(4)));
using bf16 = __hip_bfloat16;

// ---------------------------------------------------------------------------
// GEMM: C[M,N] = A[M,K] * B[N,K]^T  (A fp32 or bf16, B/C fp32)
// 128x128 tile, BK=32, 256 threads, 8x8 micro-tile per thread.
// ---------------------------------------------------------------------------
__device__ __forceinline__ void loadA4(const float* p, float* o) {
    float4 a = *(const float4*)p;
    o[0] = a.x; o[1] = a.y; o[2] = a.z; o[3] = a.w;
}
__device__ __forceinline__ void loadA4(const bf16* p, float* o) {
    ushort4 u = *(const ushort4*)p;
    o[0] = __bfloat162float(*(const bf16*)&u.x);
    o[1] = __bfloat162float(*(const bf16*)&u.y);
    o[2] = __bfloat162float(*(const bf16*)&u.z);
    o[3] = __bfloat162float(*(const bf16*)&u.w);
}

template <typename TA>
__device__ __forceinline__ void gemm_tile_128(const TA* __restrict__ A,
                                              const float* __restrict__ B,
                                              float* __restrict__ C,
                                              int bm, int bn, int N, int K) {
    __shared__ float As[32][128];   // [k][m]
    __shared__ float Bs[32][128];   // [k][n]
    const int tid = threadIdx.x;
    const int tx  = tid & 15;
    const int ty  = tid >> 4;
    float acc[8][8] = {};

    for (int k0 = 0; k0 < K; k0 += 32) {
#pragma unroll
        for (int it = 0; it < 4; ++it) {
            int idx = tid + it * 256;
            int r   = idx >> 3;
            int kq  = (idx & 7) << 2;
            float av[4];
            loadA4(&A[(size_t)(bm + r) * K + k0 + kq], av);
            As[kq + 0][r] = av[0]; As[kq + 1][r] = av[1];
            As[kq + 2][r] = av[2]; As[kq + 3][r] = av[3];
            float4 b4 = *(const float4*)&B[(size_t)(bn + r) * K + k0 + kq];
            Bs[kq + 0][r] = b4.x; Bs[kq + 1][r] = b4.y;
            Bs[kq + 2][r] = b4.z; Bs[kq + 3][r] = b4.w;
        }
        __syncthreads();
#pragma unroll
        for (int kk = 0; kk < 32; ++kk) {
            float4 a0 = *(const float4*)&As[kk][ty * 8];
            float4 a1 = *(const float4*)&As[kk][ty * 8 + 4];
            float4 b0 = *(const float4*)&Bs[kk][tx * 8];
            float4 b1 = *(const float4*)&Bs[kk][tx * 8 + 4];
            float av[8] = {a0.x, a0.y, a0.z, a0.w, a1.x, a1.y, a1.z, a1.w};
            float bv[8] = {b0.x, b0.y, b0.z, b0.w, b1.x, b1.y, b1.z, b1.w};
#pragma unroll
            for (int i = 0; i < 8; ++i)
#pragma unroll
                for (int j = 0; j < 8; ++j)
                    acc[i][j] = fmaf(av[i], bv[j], acc[i][j]);
        }
        __syncthreads();
    }
#pragma unroll
    for (int i = 0; i < 8; ++i) {
        float4 o0 = {acc[i][0], acc[i][1], acc[i][2], acc[i][3]};
        float4 o1 = {acc[i][4], acc[i][5], acc[i][6], acc[i][7]};
        size_t row = (size_t)(bm + ty * 8 + i) * N + bn + tx * 8;
        *(float4*)&C[row]     = o0;
        *(float4*)&C[row + 4] = o1;
    }
}

__global__ __launch_bounds__(256) void k_gemm_q(const float* __restrict__ x,
                                                const float* __restrict__ Wq,
                                                float* __restrict__ q) {
    gemm_tile_128(x, Wq, q, blockIdx.y * 128, blockIdx.x * 128, DIM, DIM);
}

__global__ __launch_bounds__(256) void k_gemm_kv(const float* __restrict__ x,
                                                 const float* __restrict__ Wk,
                                                 const float* __restrict__ Wv,
                                                 float* __restrict__ k,
                                                 float* __restrict__ v) {
    const int nb = blockIdx.x;
    const float* B = (nb < 4) ? Wk : Wv;
    float*       C = (nb < 4) ? k  : v;
    const int bn = (nb & 3) * 128;
    gemm_tile_128(x, B, C, blockIdx.y * 128, bn, KVD, DIM);
}

__global__ __launch_bounds__(256) void k_gemm_o(const bf16* __restrict__ a,
                                                const float* __restrict__ Wo,
                                                float* __restrict__ out) {
    gemm_tile_128(a, Wo, out, blockIdx.y * 128, blockIdx.x * 128, DIM, DIM);
}

// ---------------------------------------------------------------------------
// V transpose + bf16 cast: vbuf fp32 [SEQ][KVD] -> vt bf16 [NKV*HD][SEQ]
// grid (SEQ/64, NKV), 256 threads.
// ---------------------------------------------------------------------------
__global__ __launch_bounds__(256) void k_vt(const float* __restrict__ v,
                                            bf16* __restrict__ vt) {
    __shared__ __align__(16) bf16 vs[128][72];
    const int tid = threadIdx.x;
    const int t0  = blockIdx.x * 64;
    const int kvh = blockIdx.y;
#pragma unroll
    for (int it = 0; it < 8; ++it) {
        int idx = tid + it * 256;
        int r   = idx >> 5;            // 0..63 (token)
        int d0  = (idx & 31) * 4;      // 0..124
        float4 a = *(const float4*)&v[(size_t)(t0 + r) * KVD + kvh * HD + d0];
        vs[d0 + 0][r] = __float2bfloat16(a.x);
        vs[d0 + 1][r] = __float2bfloat16(a.y);
        vs[d0 + 2][r] = __float2bfloat16(a.z);
        vs[d0 + 3][r] = __float2bfloat16(a.w);
    }
    __syncthreads();
#pragma unroll
    for (int it = 0; it < 4; ++it) {
        int idx = tid + it * 256;
        int d   = idx >> 3;            // 0..127
        int tt  = (idx & 7) * 8;       // 0..56
        *(bf16x8*)&vt[(size_t)(kvh * HD + d) * SEQ + t0 + tt] = *(const bf16x8*)&vs[d][tt];
    }
}

// ---------------------------------------------------------------------------
// RMSNorm + RoPE (+ gain*scale for Q), fp32 in -> bf16 out.
// grid (SEQ, NH+NKV), block 128. RoPE angle quantization matches jax fp32:
// ang = fp32(t) * fp32(inv_freq), cos/sin in fp32.
// ---------------------------------------------------------------------------
__global__ __launch_bounds__(128) void k_norm_rope(const float* __restrict__ q,
                                                   const float* __restrict__ k,
                                                   const float* __restrict__ qg,
                                                   bf16* __restrict__ qb,
                                                   bf16* __restrict__ kb) {
    const int t    = blockIdx.x;
    const int head = blockIdx.y;
    const int d    = threadIdx.x;

    const float* src;
    bf16* dst;
    float gain = 1.0f;
    if (head < NH) {
        src  = q  + (size_t)t * DIM + head * HD;
        dst  = qb + (size_t)t * DIM + head * HD;
        gain = qg[head] * 0.08838834764831845f;   // fold softmax scale 128^-0.5
    } else {
        src = k  + (size_t)t * KVD + (head - NH) * HD;
        dst = kb + (size_t)t * KVD + (head - NH) * HD;
    }

    float xv = src[d];
    float ss = xv * xv;
#pragma unroll
    for (int m = 1; m <= 32; m <<= 1) ss += __shfl_xor(ss, m, 64);

    __shared__ float red[2];
    __shared__ float sh[128];
    if ((d & 63) == 0) red[d >> 6] = ss;
    __syncthreads();
    float ms  = (red[0] + red[1]) * (1.0f / 128.0f);
    float inv = 1.0f / sqrtf(ms + 1.1920928955078125e-07f);
    sh[d] = xv * inv;
    __syncthreads();

    const int i = d & 63;
    float invf = (float)pow(10000.0, -(double)i / 64.0);
    float ang  = (float)t * invf;
    float cs   = cosf(ang);
    float sn   = sinf(ang);
    float x1   = sh[i];
    float x2   = sh[i + 64];
    float outv = (d < 64) ? (x1 * cs + x2 * sn) : (x2 * cs - x1 * sn);
    dst[d] = __float2bfloat16(outv * gain);
}

// ---------------------------------------------------------------------------
// bf16 MFMA causal GQA flash attention.
// grid (SEQ/64, NH), 256 threads = 4 waves. Wave w owns q rows [16w,16w+16).
// Per kv tile (BK=64): stage K [64][136] + Vt [128][72] -> QK^T (16 mfma/wave)
// -> fp32 online softmax (16-lane shuffle groups) -> P bf16 to wave-private
// LDS -> PV (16 mfma/wave). Scale+gain pre-folded into Q.
// MFMA frag layouts (m89-verified): A/B lane l holds [l&15][(l>>4)*8+j];
// C/D: col=l&15, row=(l>>4)*4+reg.
// ---------------------------------------------------------------------------
__global__ __launch_bounds__(256) void k_attn_mfma(const bf16* __restrict__ qb,
                                                   const bf16* __restrict__ kb,
                                                   const bf16* __restrict__ vt,
                                                   bf16* __restrict__ ao) {
    __shared__ __align__(16) bf16 Ks[64][136];     // [kv][d]   pad 8
    __shared__ __align__(16) bf16 Vs[128][72];     // [d][kv]   pad 8
    __shared__ __align__(16) bf16 Ps[4][16][72];   // per-wave P [qrow][kv]

    const int tid = threadIdx.x;
    const int l   = tid & 63;
    const int w   = tid >> 6;
    const int lm  = l & 15;
    const int g   = l >> 4;
    const int qbk = gridDim.x - 1 - blockIdx.x;    // long blocks first
    const int h   = blockIdx.y;
    const int kvh = h >> 2;
    const int q0  = qbk * 64;

    // Q fragments: rows q0+16w+lm, 4 k-chunks of 32
    bf16x8 qf[4];
#pragma unroll
    for (int c = 0; c < 4; ++c)
        qf[c] = *(const bf16x8*)&qb[(size_t)(q0 + 16 * w + lm) * DIM + h * HD + c * 32 + g * 8];

    f32x4 acco[8];
#pragma unroll
    for (int dt = 0; dt < 8; ++dt) { acco[dt][0] = 0.f; acco[dt][1] = 0.f; acco[dt][2] = 0.f; acco[dt][3] = 0.f; }
    float mrow[4] = {-3e38f, -3e38f, -3e38f, -3e38f};
    float lrow[4] = {0.f, 0.f, 0.f, 0.f};

    const int ntiles = q0 / 64 + 1;
    for (int t = 0; t < ntiles; ++t) {
        const int kv0 = t * 64;
        __syncthreads();                           // readers of Ks/Vs done
#pragma unroll
        for (int it = 0; it < 4; ++it) {           // stage K (linear)
            int idx = tid + it * 256;
            int r = idx >> 4, d0 = (idx & 15) * 8;
            *(bf16x8*)&Ks[r][d0] = *(const bf16x8*)&kb[(size_t)(kv0 + r) * KVD + kvh * HD + d0];
        }
#pragma unroll
        for (int it = 0; it < 4; ++it) {           // stage V^T (linear, pre-transposed)
            int idx = tid + it * 256;
            int d = idx >> 3, tt = (idx & 7) * 8;
            *(bf16x8*)&Vs[d][tt] = *(const bf16x8*)&vt[(size_t)(kvh * HD + d) * SEQ + kv0 + tt];
        }
        __syncthreads();

        // S = Q K^T  (wave tile 16x64)
        f32x4 accs[4];
#pragma unroll
        for (int nt = 0; nt < 4; ++nt) { accs[nt][0] = 0.f; accs[nt][1] = 0.f; accs[nt][2] = 0.f; accs[nt][3] = 0.f; }
#pragma unroll
        for (int c = 0; c < 4; ++c)
#pragma unroll
            for (int nt = 0; nt < 4; ++nt) {
                bf16x8 bk = *(const bf16x8*)&Ks[nt * 16 + lm][c * 32 + g * 8];
                accs[nt] = __builtin_amdgcn_mfma_f32_16x16x32_bf16(qf[c], bk, accs[nt], 0, 0, 0);
            }

        const bool diag = (kv0 == q0);
        float alpha[4];
#pragma unroll
        for (int r = 0; r < 4; ++r) {
            const int rrow = 16 * w + 4 * g + r;   // row within block
            if (diag) {
#pragma unroll
                for (int nt = 0; nt < 4; ++nt)
                    if (nt * 16 + lm > rrow) accs[nt][r] = -3e38f;
            }
            float mt = fmaxf(fmaxf(accs[0][r], accs[1][r]), fmaxf(accs[2][r], accs[3][r]));
#pragma unroll
            for (int mm = 1; mm <= 8; mm <<= 1) mt = fmaxf(mt, __shfl_xor(mt, mm, 64));
            float mnew = fmaxf(mrow[r], mt);
            float al   = __expf(mrow[r] - mnew);
            float rs   = 0.f;
#pragma unroll
            for (int nt = 0; nt < 4; ++nt) {
                float p = __expf(accs[nt][r] - mnew);
                accs[nt][r] = p;
                rs += p;
            }
#pragma unroll
            for (int mm = 1; mm <= 8; mm <<= 1) rs += __shfl_xor(rs, mm, 64);
            mrow[r]  = mnew;
            lrow[r]  = lrow[r] * al + rs;
            alpha[r] = al;
#pragma unroll
            for (int nt = 0; nt < 4; ++nt)         // P -> wave-private LDS
                Ps[w][4 * g + r][nt * 16 + lm] = __float2bfloat16(accs[nt][r]);
        }

#pragma unroll
        for (int dt = 0; dt < 8; ++dt)
#pragma unroll
            for (int r = 0; r < 4; ++r) acco[dt][r] *= alpha[r];

        // O += P V   (wave tile 16x128)
#pragma unroll
        for (int c = 0; c < 2; ++c) {
            bf16x8 pa = *(const bf16x8*)&Ps[w][lm][c * 32 + g * 8];
#pragma unroll
            for (int dt = 0; dt < 8; ++dt) {
                bf16x8 bv = *(const bf16x8*)&Vs[dt * 16 + lm][c * 32 + g * 8];
                acco[dt] = __builtin_amdgcn_mfma_f32_16x16x32_bf16(pa, bv, acco[dt], 0, 0, 0);
            }
        }
    }

    // epilogue: O /= l, bf16 out [SEQ][DIM]
#pragma unroll
    for (int r = 0; r < 4; ++r) {
        float invl = 1.0f / lrow[r];
        size_t row = (size_t)(q0 + 16 * w + 4 * g + r) * DIM + h * HD;
#pragma unroll
        for (int dt = 0; dt < 8; ++dt)
            ao[row + dt * 16 + lm] = __float2bfloat16(acco[dt][r] * invl);
    }
}

// ---------------------------------------------------------------------------
// Workspace layout (40 MB total, under the proven 48 MB):
//   [ 0,  8M) kbuf fp32   -- consumed by norm_rope, then reused by ao
//   [ 8, 16M) vbuf fp32   -- consumed by k_vt,      then reused by ao
//   [ 0, 16M) ao bf16     -- attention output (overwrites kbuf+vbuf)
//   [16, 32M) qb bf16
//   [32, 36M) kb bf16
//   [36, 40M) vt bf16
// Q projection (fp32, 32 MB) lives in d_out until attention consumes it.
// ---------------------------------------------------------------------------
extern "C" void kernel_launch(void* const* d_in, const int* in_sizes, int n_in,
                              void* d_out, int out_size, void* d_ws, size_t ws_size,
                              hipStream_t stream) {
    const float* x  = (const float*)d_in[0];
    const float* Wq = (const float*)d_in[1];
    const float* Wk = (const float*)d_in[2];
    const float* Wv = (const float*)d_in[3];
    const float* Wo = (const float*)d_in[4];
    const float* qg = (const float*)d_in[5];
    float* out = (float*)d_out;

    char* ws = (char*)d_ws;
    float* kbuf = (float*)ws;
    float* vbuf = (float*)(ws + ((size_t)8 << 20));
    bf16*  ao   = (bf16*)ws;
    bf16*  qb   = (bf16*)(ws + ((size_t)16 << 20));
    bf16*  kb   = (bf16*)(ws + ((size_t)32 << 20));
    bf16*  vt   = (bf16*)(ws + ((size_t)36 << 20));
    float* q    = out;                       // borrow d_out for fp32 Q

    k_gemm_q   <<<dim3(DIM / 128, SEQ / 128),     256, 0, stream>>>(x, Wq, q);
    k_gemm_kv  <<<dim3(2 * KVD / 128, SEQ / 128), 256, 0, stream>>>(x, Wk, Wv, kbuf, vbuf);
    k_vt       <<<dim3(SEQ / 64, NKV),            256, 0, stream>>>(vbuf, vt);
    k_norm_rope<<<dim3(SEQ, NH + NKV),            128, 0, stream>>>(q, kbuf, qg, qb, kb);
    k_attn_mfma<<<dim3(SEQ / 64, NH),             256, 0, stream>>>(qb, kb, vt, ao);
    k_gemm_o   <<<dim3(DIM / 128, SEQ / 128),     256, 0, stream>>>(ao, Wo, out);
}

// Round 6
// 695.006 us; speedup vs baseline: 6.0648x; 2.6989x over previous
//
#include <hip/hip_runtime.h>
#include <hip/hip_bf16.h>
#include <cmath>
#include <cfloat>

#define DIM   2048
#define SEQ   4096
#define NH    16
#define NKV   4
#define HD    128
#define KVD   512   // NKV*HD

typedef __bf16 bf16x8 __attribute__((ext_vector_type(8)));
typedef float  f32x4  __attribute__((ext_vector_type(4)));
using bf16 = __hip_bfloat16;

// ---------------------------------------------------------------------------
// async global->LDS, 16B per lane. LDS dest must be wave-uniform base; HW
// places lane l's 16B at base + l*16 (m97/m104).
// ---------------------------------------------------------------------------
typedef __attribute__((address_space(1))) const unsigned int gu32;
typedef __attribute__((address_space(3))) unsigned int lu32;
__device__ __forceinline__ void gload_lds16(const bf16* g, bf16* l) {
    __builtin_amdgcn_global_load_lds((gu32*)g, (lu32*)l, 16, 0, 0);
}

// ---------------------------------------------------------------------------
// fp32 -> bf16 cast, 8 elems/thread.
// ---------------------------------------------------------------------------
__global__ __launch_bounds__(256) void k_cast8(const float* __restrict__ in,
                                               bf16* __restrict__ out, int n8) {
    int i = blockIdx.x * 256 + threadIdx.x;
    if (i >= n8) return;
    const float4* p = (const float4*)in + 2 * (size_t)i;
    float4 a = p[0], b = p[1];
    bf16x8 o;
    o[0] = (__bf16)a.x; o[1] = (__bf16)a.y; o[2] = (__bf16)a.z; o[3] = (__bf16)a.w;
    o[4] = (__bf16)b.x; o[5] = (__bf16)b.y; o[6] = (__bf16)b.z; o[7] = (__bf16)b.w;
    *(bf16x8*)(out + 8 * (size_t)i) = o;
}

// ---------------------------------------------------------------------------
// bf16 MFMA GEMM: C[M,N] = A[M,K] * B[N,K]^T, m97 structure.
// 128x128 tile, BK=32, 256 threads (4 waves, 2x2), 16 mfma_16x16x32/wave/iter.
// LDS: As/Bs [128 rows][32 k] linear bf16 (8 KB each), global_load_lds w=16.
// Frags (m89-verified): A/B lane l = row (base+l&15), k = (l>>4)*8..+8 per
// 32-chunk; C/D col=l&15, row=(l>>4)*4+reg.
// ---------------------------------------------------------------------------
template <typename TC>
__device__ __forceinline__ void gemm_bf16_128(const bf16* __restrict__ A,
                                              const bf16* __restrict__ B,
                                              TC* __restrict__ C,
                                              int bm, int bn, int N, int K) {
    __shared__ __align__(16) bf16 As[128 * 32];
    __shared__ __align__(16) bf16 Bs[128 * 32];
    const int tid = threadIdx.x;
    const int l   = tid & 63;
    const int w   = tid >> 6;
    const int lm  = l & 15;
    const int g   = l >> 4;
    const int wr  = w >> 1;
    const int wc  = w & 1;
    const int rq  = l >> 2;          // row within 16-row chunk
    const int kq  = (l & 3) * 8;     // k offset within BK=32

    f32x4 acc[4][4];
#pragma unroll
    for (int mi = 0; mi < 4; ++mi)
#pragma unroll
        for (int ni = 0; ni < 4; ++ni) {
            acc[mi][ni][0] = 0.f; acc[mi][ni][1] = 0.f;
            acc[mi][ni][2] = 0.f; acc[mi][ni][3] = 0.f;
        }

    // wave w stages 16-row chunks {w, w+4} of A and of B
    const bf16* Ap0 = A + (size_t)(bm + w * 16 + rq) * K + kq;
    const bf16* Ap1 = Ap0 + (size_t)64 * K;
    const bf16* Bp0 = B + (size_t)(bn + w * 16 + rq) * K + kq;
    const bf16* Bp1 = Bp0 + (size_t)64 * K;
    bf16* lA0 = &As[w * 512];
    bf16* lA1 = &As[(w + 4) * 512];
    bf16* lB0 = &Bs[w * 512];
    bf16* lB1 = &Bs[(w + 4) * 512];

    for (int k0 = 0; k0 < K; k0 += 32) {
        gload_lds16(Ap0 + k0, lA0);
        gload_lds16(Ap1 + k0, lA1);
        gload_lds16(Bp0 + k0, lB0);
        gload_lds16(Bp1 + k0, lB1);
        __syncthreads();                       // drains vmcnt, LDS visible
        bf16x8 af[4], bfv[4];
#pragma unroll
        for (int mi = 0; mi < 4; ++mi)
            af[mi] = *(const bf16x8*)&As[(wr * 64 + mi * 16 + lm) * 32 + g * 8];
#pragma unroll
        for (int ni = 0; ni < 4; ++ni)
            bfv[ni] = *(const bf16x8*)&Bs[(wc * 64 + ni * 16 + lm) * 32 + g * 8];
#pragma unroll
        for (int mi = 0; mi < 4; ++mi)
#pragma unroll
            for (int ni = 0; ni < 4; ++ni)
                acc[mi][ni] = __builtin_amdgcn_mfma_f32_16x16x32_bf16(af[mi], bfv[ni], acc[mi][ni], 0, 0, 0);
        __syncthreads();                       // readers done before next stage
    }

#pragma unroll
    for (int mi = 0; mi < 4; ++mi)
#pragma unroll
        for (int rr = 0; rr < 4; ++rr) {
            size_t row = (size_t)(bm + wr * 64 + mi * 16 + g * 4 + rr) * N;
#pragma unroll
            for (int ni = 0; ni < 4; ++ni) {
                float vv = acc[mi][ni][rr];
                int col = bn + wc * 64 + ni * 16 + lm;
                if constexpr (sizeof(TC) == 2) C[row + col] = __float2bfloat16(vv);
                else                           C[row + col] = vv;
            }
        }
}

__global__ __launch_bounds__(256) void k_gemm_q(const bf16* __restrict__ xb,
                                                const bf16* __restrict__ Wqb,
                                                bf16* __restrict__ qb) {
    gemm_bf16_128<bf16>(xb, Wqb, qb, blockIdx.y * 128, blockIdx.x * 128, DIM, DIM);
}

__global__ __launch_bounds__(256) void k_gemm_kv(const bf16* __restrict__ xb,
                                                 const bf16* __restrict__ Wkb,
                                                 const bf16* __restrict__ Wvb,
                                                 bf16* __restrict__ kr,
                                                 bf16* __restrict__ vr) {
    const int nb = blockIdx.x;                 // 0..7
    const bf16* B = (nb < 4) ? Wkb : Wvb;
    bf16*       Cc = (nb < 4) ? kr  : vr;
    gemm_bf16_128<bf16>(xb, B, Cc, blockIdx.y * 128, (nb & 3) * 128, KVD, DIM);
}

__global__ __launch_bounds__(256) void k_gemm_o(const bf16* __restrict__ ao,
                                                const bf16* __restrict__ Wob,
                                                float* __restrict__ out) {
    gemm_bf16_128<float>(ao, Wob, out, blockIdx.y * 128, blockIdx.x * 128, DIM, DIM);
}

// ---------------------------------------------------------------------------
// V transpose: v bf16 [SEQ][KVD] -> vt bf16 [NKV*HD][SEQ]. grid (SEQ/64, NKV).
// ---------------------------------------------------------------------------
__global__ __launch_bounds__(256) void k_vt(const bf16* __restrict__ v,
                                            bf16* __restrict__ vt) {
    __shared__ __align__(16) bf16 vs[128][72];
    const int tid = threadIdx.x;
    const int t0  = blockIdx.x * 64;
    const int kvh = blockIdx.y;
#pragma unroll
    for (int it = 0; it < 4; ++it) {
        int idx = tid + it * 256;
        int r   = idx >> 4;            // 0..63 token
        int d0  = (idx & 15) * 8;
        bf16x8 a = *(const bf16x8*)&v[(size_t)(t0 + r) * KVD + kvh * HD + d0];
#pragma unroll
        for (int j = 0; j < 8; ++j) *(__bf16*)&vs[d0 + j][r] = a[j];
    }
    __syncthreads();
#pragma unroll
    for (int it = 0; it < 4; ++it) {
        int idx = tid + it * 256;
        int d   = idx >> 3;
        int tt  = (idx & 7) * 8;
        *(bf16x8*)&vt[(size_t)(kvh * HD + d) * SEQ + t0 + tt] = *(const bf16x8*)&vs[d][tt];
    }
}

// ---------------------------------------------------------------------------
// RMSNorm + RoPE (+ gain*scale for Q), bf16 in-place. grid (SEQ, NH+NKV).
// ---------------------------------------------------------------------------
__global__ __launch_bounds__(128) void k_norm_rope(bf16* __restrict__ q,
                                                   bf16* __restrict__ k,
                                                   const float* __restrict__ qg) {
    const int t    = blockIdx.x;
    const int head = blockIdx.y;
    const int d    = threadIdx.x;

    bf16* base;
    float gain = 1.0f;
    if (head < NH) {
        base = q + (size_t)t * DIM + head * HD;
        gain = qg[head] * 0.08838834764831845f;   // fold softmax scale 128^-0.5
    } else {
        base = k + (size_t)t * KVD + (head - NH) * HD;
    }

    float xv = __bfloat162float(base[d]);
    float ss = xv * xv;
#pragma unroll
    for (int m = 1; m <= 32; m <<= 1) ss += __shfl_xor(ss, m, 64);

    __shared__ float red[2];
    __shared__ float sh[128];
    if ((d & 63) == 0) red[d >> 6] = ss;
    __syncthreads();
    float ms  = (red[0] + red[1]) * (1.0f / 128.0f);
    float inv = 1.0f / sqrtf(ms + 1.1920928955078125e-07f);
    sh[d] = xv * inv;
    __syncthreads();

    const int i = d & 63;
    float invf = (float)pow(10000.0, -(double)i / 64.0);
    float ang  = (float)t * invf;
    float cs   = cosf(ang);
    float sn   = sinf(ang);
    float x1   = sh[i];
    float x2   = sh[i + 64];
    float outv = (d < 64) ? (x1 * cs + x2 * sn) : (x2 * cs - x1 * sn);
    base[d] = __float2bfloat16(outv * gain);
}

// ---------------------------------------------------------------------------
// bf16 MFMA causal GQA flash attention + async-STAGE split (T14):
// next tile's K/V global loads issue into regs right after the current tile's
// LDS writes, hiding HBM latency under QK/softmax/PV.
// grid (SEQ/64, NH), 256 threads = 4 waves, BQ=64 (16 q-rows/wave), BK=64.
// ---------------------------------------------------------------------------
__global__ __launch_bounds__(256) void k_attn_mfma(const bf16* __restrict__ qb,
                                                   const bf16* __restrict__ kb,
                                                   const bf16* __restrict__ vt,
                                                   bf16* __restrict__ ao) {
    __shared__ __align__(16) bf16 Ks[64][136];     // [kv][d]   pad 8
    __shared__ __align__(16) bf16 Vs[128][72];     // [d][kv]   pad 8
    __shared__ __align__(16) bf16 Ps[4][16][72];   // per-wave P [qrow][kv]

    const int tid = threadIdx.x;
    const int l   = tid & 63;
    const int w   = tid >> 6;
    const int lm  = l & 15;
    const int g   = l >> 4;
    const int qbk = gridDim.x - 1 - blockIdx.x;    // long blocks first
    const int h   = blockIdx.y;
    const int kvh = h >> 2;
    const int q0  = qbk * 64;

    bf16x8 qf[4];
#pragma unroll
    for (int c = 0; c < 4; ++c)
        qf[c] = *(const bf16x8*)&qb[(size_t)(q0 + 16 * w + lm) * DIM + h * HD + c * 32 + g * 8];

    f32x4 acco[8];
#pragma unroll
    for (int dt = 0; dt < 8; ++dt) { acco[dt][0] = 0.f; acco[dt][1] = 0.f; acco[dt][2] = 0.f; acco[dt][3] = 0.f; }
    float mrow[4] = {-3e38f, -3e38f, -3e38f, -3e38f};
    float lrow[4] = {0.f, 0.f, 0.f, 0.f};

    bf16x8 kreg[4], vreg[4];
#define ISSUE(KV0)                                                              \
    do {                                                                        \
        _Pragma("unroll") for (int it = 0; it < 4; ++it) {                      \
            int idx = tid + it * 256;                                           \
            int r = idx >> 4, d0 = (idx & 15) * 8;                              \
            kreg[it] = *(const bf16x8*)&kb[(size_t)((KV0) + r) * KVD + kvh * HD + d0]; \
        }                                                                       \
        _Pragma("unroll") for (int it = 0; it < 4; ++it) {                      \
            int idx = tid + it * 256;                                           \
            int d = idx >> 3, tt = (idx & 7) * 8;                               \
            vreg[it] = *(const bf16x8*)&vt[(size_t)(kvh * HD + d) * SEQ + (KV0) + tt]; \
        }                                                                       \
    } while (0)

    ISSUE(0);
    const int ntiles = q0 / 64 + 1;
    for (int t = 0; t < ntiles; ++t) {
        const int kv0 = t * 64;
        __syncthreads();                           // prev readers of Ks/Vs done
#pragma unroll
        for (int it = 0; it < 4; ++it) {
            int idx = tid + it * 256;
            int r = idx >> 4, d0 = (idx & 15) * 8;
            *(bf16x8*)&Ks[r][d0] = kreg[it];
        }
#pragma unroll
        for (int it = 0; it < 4; ++it) {
            int idx = tid + it * 256;
            int d = idx >> 3, tt = (idx & 7) * 8;
            *(bf16x8*)&Vs[d][tt] = vreg[it];
        }
        __syncthreads();
        if (t + 1 < ntiles) ISSUE(kv0 + 64);       // prefetch under compute

        // S = Q K^T (wave tile 16x64)
        f32x4 accs[4];
#pragma unroll
        for (int nt = 0; nt < 4; ++nt) { accs[nt][0] = 0.f; accs[nt][1] = 0.f; accs[nt][2] = 0.f; accs[nt][3] = 0.f; }
#pragma unroll
        for (int c = 0; c < 4; ++c)
#pragma unroll
            for (int nt = 0; nt < 4; ++nt) {
                bf16x8 bk = *(const bf16x8*)&Ks[nt * 16 + lm][c * 32 + g * 8];
                accs[nt] = __builtin_amdgcn_mfma_f32_16x16x32_bf16(qf[c], bk, accs[nt], 0, 0, 0);
            }

        const bool diag = (kv0 == q0);
        float alpha[4];
#pragma unroll
        for (int r = 0; r < 4; ++r) {
            const int rrow = 16 * w + 4 * g + r;
            if (diag) {
#pragma unroll
                for (int nt = 0; nt < 4; ++nt)
                    if (nt * 16 + lm > rrow) accs[nt][r] = -3e38f;
            }
            float mt = fmaxf(fmaxf(accs[0][r], accs[1][r]), fmaxf(accs[2][r], accs[3][r]));
#pragma unroll
            for (int mm = 1; mm <= 8; mm <<= 1) mt = fmaxf(mt, __shfl_xor(mt, mm, 64));
            float mnew = fmaxf(mrow[r], mt);
            float al   = __expf(mrow[r] - mnew);
            float rs   = 0.f;
#pragma unroll
            for (int nt = 0; nt < 4; ++nt) {
                float p = __expf(accs[nt][r] - mnew);
                accs[nt][r] = p;
                rs += p;
            }
#pragma unroll
            for (int mm = 1; mm <= 8; mm <<= 1) rs += __shfl_xor(rs, mm, 64);
            mrow[r]  = mnew;
            lrow[r]  = lrow[r] * al + rs;
            alpha[r] = al;
#pragma unroll
            for (int nt = 0; nt < 4; ++nt)
                Ps[w][4 * g + r][nt * 16 + lm] = __float2bfloat16(accs[nt][r]);
        }

#pragma unroll
        for (int dt = 0; dt < 8; ++dt)
#pragma unroll
            for (int r = 0; r < 4; ++r) acco[dt][r] *= alpha[r];

        // O += P V (wave tile 16x128)
#pragma unroll
        for (int c = 0; c < 2; ++c) {
            bf16x8 pa = *(const bf16x8*)&Ps[w][lm][c * 32 + g * 8];
#pragma unroll
            for (int dt = 0; dt < 8; ++dt) {
                bf16x8 bv = *(const bf16x8*)&Vs[dt * 16 + lm][c * 32 + g * 8];
                acco[dt] = __builtin_amdgcn_mfma_f32_16x16x32_bf16(pa, bv, acco[dt], 0, 0, 0);
            }
        }
    }
#undef ISSUE

#pragma unroll
    for (int r = 0; r < 4; ++r) {
        float invl = 1.0f / lrow[r];
        size_t row = (size_t)(q0 + 16 * w + 4 * g + r) * DIM + h * HD;
#pragma unroll
        for (int dt = 0; dt < 8; ++dt)
            ao[row + dt * 16 + lm] = __float2bfloat16(acco[dt][r] * invl);
    }
}

// ---------------------------------------------------------------------------
// Workspace (exactly 48 MB, region-reused; stream order makes each safe):
//   [ 0,16) qb            (written by gemm_q, normed in place)
//   [16,20) kraw/kb       (gemm_kv, normed in place)
//   [20,22) Wkb  -> vt[20,24) after k_vt
//   [22,24) Wvb
//   [24,40) xb   -> ao    (xb dead after gemm_kv)
//   [40,48) Wqb  -> vraw[40,44) after gemm_q -> Wob[40,48) after k_vt
// ---------------------------------------------------------------------------
extern "C" void kernel_launch(void* const* d_in, const int* in_sizes, int n_in,
                              void* d_out, int out_size, void* d_ws, size_t ws_size,
                              hipStream_t stream) {
    const float* x  = (const float*)d_in[0];
    const float* Wq = (const float*)d_in[1];
    const float* Wk = (const float*)d_in[2];
    const float* Wv = (const float*)d_in[3];
    const float* Wo = (const float*)d_in[4];
    const float* qg = (const float*)d_in[5];
    float* out = (float*)d_out;

    char* ws = (char*)d_ws;
    const size_t MB = 1u << 20;
    bf16* qb   = (bf16*)(ws);
    bf16* kb   = (bf16*)(ws + 16 * MB);
    bf16* Wkb  = (bf16*)(ws + 20 * MB);
    bf16* Wvb  = (bf16*)(ws + 22 * MB);
    bf16* vt   = (bf16*)(ws + 20 * MB);
    bf16* xb   = (bf16*)(ws + 24 * MB);
    bf16* ao   = (bf16*)(ws + 24 * MB);
    bf16* Wqb  = (bf16*)(ws + 40 * MB);
    bf16* vraw = (bf16*)(ws + 40 * MB);
    bf16* Wob  = (bf16*)(ws + 40 * MB);

    k_cast8<<<4096, 256, 0, stream>>>(x,  xb,  1048576);
    k_cast8<<<2048, 256, 0, stream>>>(Wq, Wqb,  524288);
    k_cast8<<< 512, 256, 0, stream>>>(Wk, Wkb,  131072);
    k_cast8<<< 512, 256, 0, stream>>>(Wv, Wvb,  131072);
    k_gemm_q   <<<dim3(DIM / 128, SEQ / 128), 256, 0, stream>>>(xb, Wqb, qb);
    k_gemm_kv  <<<dim3(8, SEQ / 128),         256, 0, stream>>>(xb, Wkb, Wvb, kb, vraw);
    k_vt       <<<dim3(SEQ / 64, NKV),        256, 0, stream>>>(vraw, vt);
    k_cast8<<<2048, 256, 0, stream>>>(Wo, Wob,  524288);
    k_norm_rope<<<dim3(SEQ, NH + NKV),        128, 0, stream>>>(qb, kb, qg);
    k_attn_mfma<<<dim3(SEQ / 64, NH),         256, 0, stream>>>(qb, kb, vt, ao);
    k_gemm_o   <<<dim3(DIM / 128, SEQ / 128), 256, 0, stream>>>(ao, Wob, out);
}

// Round 7
// 578.023 us; speedup vs baseline: 7.2922x; 1.2024x over previous
//
#include <hip/hip_runtime.h>
#include <hip/hip_bf16.h>
#include <cmath>
#include <cfloat>

#define DIM   2048
#define SEQ   4096
#define NH    16
#define NKV   4
#define HD    128
#define KVD   512   // NKV*HD

typedef __bf16 bf16x8 __attribute__((ext_vector_type(8)));
typedef float  f32x4  __attribute__((ext_vector_type(4)));
using bf16 = __hip_bfloat16;

// ---------------------------------------------------------------------------
// async global->LDS, 16B per lane. LDS dest must be wave-uniform base; HW
// places lane l's 16B at base + l*16 (m97/m104).
// ---------------------------------------------------------------------------
typedef __attribute__((address_space(1))) const unsigned int gu32;
typedef __attribute__((address_space(3))) unsigned int lu32;
__device__ __forceinline__ void gload_lds16(const bf16* g, bf16* l) {
    __builtin_amdgcn_global_load_lds((gu32*)g, (lu32*)l, 16, 0, 0);
}

// ---------------------------------------------------------------------------
// fp32 -> bf16 cast, 8 elems/thread.
// ---------------------------------------------------------------------------
__global__ __launch_bounds__(256) void k_cast8(const float* __restrict__ in,
                                               bf16* __restrict__ out, int n8) {
    int i = blockIdx.x * 256 + threadIdx.x;
    if (i >= n8) return;
    const float4* p = (const float4*)in + 2 * (size_t)i;
    float4 a = p[0], b = p[1];
    bf16x8 o;
    o[0] = (__bf16)a.x; o[1] = (__bf16)a.y; o[2] = (__bf16)a.z; o[3] = (__bf16)a.w;
    o[4] = (__bf16)b.x; o[5] = (__bf16)b.y; o[6] = (__bf16)b.z; o[7] = (__bf16)b.w;
    *(bf16x8*)(out + 8 * (size_t)i) = o;
}

// ---------------------------------------------------------------------------
// bf16 MFMA GEMM: C[M,N] = A[M,K] * B[N,K]^T, m97 structure.
// 128x128 tile, BK=32, 256 threads (4 waves, 2x2), 16 mfma_16x16x32/wave/iter.
// ---------------------------------------------------------------------------
template <typename TC>
__device__ __forceinline__ void gemm_bf16_128(const bf16* __restrict__ A,
                                              const bf16* __restrict__ B,
                                              TC* __restrict__ C,
                                              int bm, int bn, int N, int K) {
    __shared__ __align__(16) bf16 As[128 * 32];
    __shared__ __align__(16) bf16 Bs[128 * 32];
    const int tid = threadIdx.x;
    const int l   = tid & 63;
    const int w   = tid >> 6;
    const int lm  = l & 15;
    const int g   = l >> 4;
    const int wr  = w >> 1;
    const int wc  = w & 1;
    const int rq  = l >> 2;          // row within 16-row chunk
    const int kq  = (l & 3) * 8;     // k offset within BK=32

    f32x4 acc[4][4];
#pragma unroll
    for (int mi = 0; mi < 4; ++mi)
#pragma unroll
        for (int ni = 0; ni < 4; ++ni) {
            acc[mi][ni][0] = 0.f; acc[mi][ni][1] = 0.f;
            acc[mi][ni][2] = 0.f; acc[mi][ni][3] = 0.f;
        }

    const bf16* Ap0 = A + (size_t)(bm + w * 16 + rq) * K + kq;
    const bf16* Ap1 = Ap0 + (size_t)64 * K;
    const bf16* Bp0 = B + (size_t)(bn + w * 16 + rq) * K + kq;
    const bf16* Bp1 = Bp0 + (size_t)64 * K;
    bf16* lA0 = &As[w * 512];
    bf16* lA1 = &As[(w + 4) * 512];
    bf16* lB0 = &Bs[w * 512];
    bf16* lB1 = &Bs[(w + 4) * 512];

    for (int k0 = 0; k0 < K; k0 += 32) {
        gload_lds16(Ap0 + k0, lA0);
        gload_lds16(Ap1 + k0, lA1);
        gload_lds16(Bp0 + k0, lB0);
        gload_lds16(Bp1 + k0, lB1);
        __syncthreads();                       // drains vmcnt, LDS visible
        bf16x8 af[4], bfv[4];
#pragma unroll
        for (int mi = 0; mi < 4; ++mi)
            af[mi] = *(const bf16x8*)&As[(wr * 64 + mi * 16 + lm) * 32 + g * 8];
#pragma unroll
        for (int ni = 0; ni < 4; ++ni)
            bfv[ni] = *(const bf16x8*)&Bs[(wc * 64 + ni * 16 + lm) * 32 + g * 8];
#pragma unroll
        for (int mi = 0; mi < 4; ++mi)
#pragma unroll
            for (int ni = 0; ni < 4; ++ni)
                acc[mi][ni] = __builtin_amdgcn_mfma_f32_16x16x32_bf16(af[mi], bfv[ni], acc[mi][ni], 0, 0, 0);
        __syncthreads();                       // readers done before next stage
    }

#pragma unroll
    for (int mi = 0; mi < 4; ++mi)
#pragma unroll
        for (int rr = 0; rr < 4; ++rr) {
            size_t row = (size_t)(bm + wr * 64 + mi * 16 + g * 4 + rr) * N;
#pragma unroll
            for (int ni = 0; ni < 4; ++ni) {
                float vv = acc[mi][ni][rr];
                int col = bn + wc * 64 + ni * 16 + lm;
                if constexpr (sizeof(TC) == 2) C[row + col] = __float2bfloat16(vv);
                else                           C[row + col] = vv;
            }
        }
}

__global__ __launch_bounds__(256) void k_gemm_q(const bf16* __restrict__ xb,
                                                const bf16* __restrict__ Wqb,
                                                bf16* __restrict__ qb) {
    gemm_bf16_128<bf16>(xb, Wqb, qb, blockIdx.y * 128, blockIdx.x * 128, DIM, DIM);
}

__global__ __launch_bounds__(256) void k_gemm_kv(const bf16* __restrict__ xb,
                                                 const bf16* __restrict__ Wkb,
                                                 const bf16* __restrict__ Wvb,
                                                 bf16* __restrict__ kr,
                                                 bf16* __restrict__ vr) {
    const int nb = blockIdx.x;                 // 0..7
    const bf16* B = (nb < 4) ? Wkb : Wvb;
    bf16*       Cc = (nb < 4) ? kr  : vr;
    gemm_bf16_128<bf16>(xb, B, Cc, blockIdx.y * 128, (nb & 3) * 128, KVD, DIM);
}

__global__ __launch_bounds__(256) void k_gemm_o(const bf16* __restrict__ ao,
                                                const bf16* __restrict__ Wob,
                                                float* __restrict__ out) {
    gemm_bf16_128<float>(ao, Wob, out, blockIdx.y * 128, blockIdx.x * 128, DIM, DIM);
}

// ---------------------------------------------------------------------------
// V transpose: v bf16 [SEQ][KVD] -> vt bf16 [NKV*HD][SEQ]. grid (SEQ/64, NKV).
// ---------------------------------------------------------------------------
__global__ __launch_bounds__(256) void k_vt(const bf16* __restrict__ v,
                                            bf16* __restrict__ vt) {
    __shared__ __align__(16) bf16 vs[128][72];
    const int tid = threadIdx.x;
    const int t0  = blockIdx.x * 64;
    const int kvh = blockIdx.y;
#pragma unroll
    for (int it = 0; it < 4; ++it) {
        int idx = tid + it * 256;
        int r   = idx >> 4;            // 0..63 token
        int d0  = (idx & 15) * 8;
        bf16x8 a = *(const bf16x8*)&v[(size_t)(t0 + r) * KVD + kvh * HD + d0];
#pragma unroll
        for (int j = 0; j < 8; ++j) *(__bf16*)&vs[d0 + j][r] = a[j];
    }
    __syncthreads();
#pragma unroll
    for (int it = 0; it < 4; ++it) {
        int idx = tid + it * 256;
        int d   = idx >> 3;
        int tt  = (idx & 7) * 8;
        *(bf16x8*)&vt[(size_t)(kvh * HD + d) * SEQ + t0 + tt] = *(const bf16x8*)&vs[d][tt];
    }
}

// ---------------------------------------------------------------------------
// RMSNorm + RoPE (+ gain*scale for Q), bf16 in-place. grid (SEQ, NH+NKV).
// ---------------------------------------------------------------------------
__global__ __launch_bounds__(128) void k_norm_rope(bf16* __restrict__ q,
                                                   bf16* __restrict__ k,
                                                   const float* __restrict__ qg) {
    const int t    = blockIdx.x;
    const int head = blockIdx.y;
    const int d    = threadIdx.x;

    bf16* base;
    float gain = 1.0f;
    if (head < NH) {
        base = q + (size_t)t * DIM + head * HD;
        gain = qg[head] * 0.08838834764831845f;   // fold softmax scale 128^-0.5
    } else {
        base = k + (size_t)t * KVD + (head - NH) * HD;
    }

    float xv = __bfloat162float(base[d]);
    float ss = xv * xv;
#pragma unroll
    for (int m = 1; m <= 32; m <<= 1) ss += __shfl_xor(ss, m, 64);

    __shared__ float red[2];
    __shared__ float sh[128];
    if ((d & 63) == 0) red[d >> 6] = ss;
    __syncthreads();
    float ms  = (red[0] + red[1]) * (1.0f / 128.0f);
    float inv = 1.0f / sqrtf(ms + 1.1920928955078125e-07f);
    sh[d] = xv * inv;
    __syncthreads();

    const int i = d & 63;
    float invf = (float)pow(10000.0, -(double)i / 64.0);
    float ang  = (float)t * invf;
    float cs   = cosf(ang);
    float sn   = sinf(ang);
    float x1   = sh[i];
    float x2   = sh[i + 64];
    float outv = (d < 64) ? (x1 * cs + x2 * sn) : (x2 * cs - x1 * sn);
    base[d] = __float2bfloat16(outv * gain);
}

// ---------------------------------------------------------------------------
// Online-softmax update for one pass (4 rows/lane-group, 16-lane groups).
// ---------------------------------------------------------------------------
__device__ __forceinline__ void sm_pass(f32x4* accs, bool diag, int w, int g, int lm,
                                        float* mrow, float* lrow, float* alpha,
                                        bf16 (*PsW)[72]) {
#pragma unroll
    for (int r = 0; r < 4; ++r) {
        const int rrow = 16 * w + 4 * g + r;
        if (diag) {
#pragma unroll
            for (int nt = 0; nt < 4; ++nt)
                if (nt * 16 + lm > rrow) accs[nt][r] = -3e38f;
        }
        float mt = fmaxf(fmaxf(accs[0][r], accs[1][r]), fmaxf(accs[2][r], accs[3][r]));
#pragma unroll
        for (int mm = 1; mm <= 8; mm <<= 1) mt = fmaxf(mt, __shfl_xor(mt, mm, 64));
        float mnew = fmaxf(mrow[r], mt);
        float al   = __expf(mrow[r] - mnew);
        float rs   = 0.f;
#pragma unroll
        for (int nt = 0; nt < 4; ++nt) {
            float p = __expf(accs[nt][r] - mnew);
            accs[nt][r] = p;
            rs += p;
        }
#pragma unroll
        for (int mm = 1; mm <= 8; mm <<= 1) rs += __shfl_xor(rs, mm, 64);
        mrow[r]  = mnew;
        lrow[r]  = lrow[r] * al + rs;
        alpha[r] = al;
#pragma unroll
        for (int nt = 0; nt < 4; ++nt)
            PsW[4 * g + r][nt * 16 + lm] = __float2bfloat16(accs[nt][r]);
    }
}

// ---------------------------------------------------------------------------
// bf16 MFMA causal GQA flash attention, CAUSAL-PAIRED for load balance:
// block handles q-blocks {i, 63-i} -> exactly 65 MFMA-tile-units per block,
// 512 equal blocks = 2/CU, zero tail. Pass A's KV range is a prefix of pass
// B's, so K/V staging is shared (halved). T14 reg-prefetch + T5 setprio.
// XCD swizzle groups head-pairs sharing a KV head (KV 2MB <= 4MB L2/XCD).
// ---------------------------------------------------------------------------
__global__ __launch_bounds__(256, 2) void k_attn_mfma(const bf16* __restrict__ qb,
                                                      const bf16* __restrict__ kb,
                                                      const bf16* __restrict__ vt,
                                                      bf16* __restrict__ ao) {
    __shared__ __align__(16) bf16 Ks[64][136];       // [kv][d]   pad 8
    __shared__ __align__(16) bf16 Vs[128][72];       // [d][kv]   pad 8
    __shared__ __align__(16) bf16 Ps[4][2][16][72];  // per-wave, per-pass P

    const int tid = threadIdx.x;
    const int l   = tid & 63;
    const int w   = tid >> 6;
    const int lm  = l & 15;
    const int g   = l >> 4;
    const int bid  = blockIdx.x;                   // 0..511
    const int orig = (bid & 7) * 64 + (bid >> 3);  // XCD-contiguous (512%8==0)
    const int i    = orig & 31;                    // pair index
    const int h    = orig >> 5;                    // head
    const int kvh  = h >> 2;
    const int q0A  = i * 64;                       // short pass: tiles 0..i
    const int q0B  = (63 - i) * 64;                // long pass:  tiles 0..63-i

    bf16x8 qfA[4], qfB[4];
#pragma unroll
    for (int c = 0; c < 4; ++c) {
        qfA[c] = *(const bf16x8*)&qb[(size_t)(q0A + 16 * w + lm) * DIM + h * HD + c * 32 + g * 8];
        qfB[c] = *(const bf16x8*)&qb[(size_t)(q0B + 16 * w + lm) * DIM + h * HD + c * 32 + g * 8];
    }

    f32x4 accoA[8], accoB[8];
#pragma unroll
    for (int dt = 0; dt < 8; ++dt)
#pragma unroll
        for (int r = 0; r < 4; ++r) { accoA[dt][r] = 0.f; accoB[dt][r] = 0.f; }
    float mrowA[4] = {-3e38f, -3e38f, -3e38f, -3e38f};
    float mrowB[4] = {-3e38f, -3e38f, -3e38f, -3e38f};
    float lrowA[4] = {0.f, 0.f, 0.f, 0.f};
    float lrowB[4] = {0.f, 0.f, 0.f, 0.f};

    bf16x8 kreg[4], vreg[4];
#define ISSUE(KV0)                                                              \
    do {                                                                        \
        _Pragma("unroll") for (int it = 0; it < 4; ++it) {                      \
            int idx = tid + it * 256;                                           \
            int r = idx >> 4, d0 = (idx & 15) * 8;                              \
            kreg[it] = *(const bf16x8*)&kb[(size_t)((KV0) + r) * KVD + kvh * HD + d0]; \
        }                                                                       \
        _Pragma("unroll") for (int it = 0; it < 4; ++it) {                      \
            int idx = tid + it * 256;                                           \
            int d = idx >> 3, tt = (idx & 7) * 8;                               \
            vreg[it] = *(const bf16x8*)&vt[(size_t)(kvh * HD + d) * SEQ + (KV0) + tt]; \
        }                                                                       \
    } while (0)

    ISSUE(0);
    const int ntiles = 64 - i;                     // pass B tile count
    for (int t = 0; t < ntiles; ++t) {
        const int kv0 = t * 64;
        __syncthreads();                           // prev readers of Ks/Vs done
#pragma unroll
        for (int it = 0; it < 4; ++it) {
            int idx = tid + it * 256;
            int r = idx >> 4, d0 = (idx & 15) * 8;
            *(bf16x8*)&Ks[r][d0] = kreg[it];
        }
#pragma unroll
        for (int it = 0; it < 4; ++it) {
            int idx = tid + it * 256;
            int d = idx >> 3, tt = (idx & 7) * 8;
            *(bf16x8*)&Vs[d][tt] = vreg[it];
        }
        __syncthreads();
        if (t + 1 < ntiles) ISSUE(kv0 + 64);       // prefetch under compute

        const bool actA = (t <= i);

        // S = Q K^T for both passes (16 mfma each, shared Ks)
        f32x4 sB[4], sA[4];
#pragma unroll
        for (int nt = 0; nt < 4; ++nt)
#pragma unroll
            for (int r = 0; r < 4; ++r) { sB[nt][r] = 0.f; sA[nt][r] = 0.f; }
        __builtin_amdgcn_s_setprio(1);
#pragma unroll
        for (int c = 0; c < 4; ++c)
#pragma unroll
            for (int nt = 0; nt < 4; ++nt) {
                bf16x8 bk = *(const bf16x8*)&Ks[nt * 16 + lm][c * 32 + g * 8];
                sB[nt] = __builtin_amdgcn_mfma_f32_16x16x32_bf16(qfB[c], bk, sB[nt], 0, 0, 0);
            }
        if (actA) {
#pragma unroll
            for (int c = 0; c < 4; ++c)
#pragma unroll
                for (int nt = 0; nt < 4; ++nt) {
                    bf16x8 bk = *(const bf16x8*)&Ks[nt * 16 + lm][c * 32 + g * 8];
                    sA[nt] = __builtin_amdgcn_mfma_f32_16x16x32_bf16(qfA[c], bk, sA[nt], 0, 0, 0);
                }
        }
        __builtin_amdgcn_s_setprio(0);

        // online softmax, both passes (independent chains -> ILP)
        float alB[4], alA[4];
        sm_pass(sB, t == ntiles - 1, w, g, lm, mrowB, lrowB, alB, Ps[w][0]);
        if (actA) sm_pass(sA, t == i, w, g, lm, mrowA, lrowA, alA, Ps[w][1]);

#pragma unroll
        for (int dt = 0; dt < 8; ++dt)
#pragma unroll
            for (int r = 0; r < 4; ++r) {
                accoB[dt][r] *= alB[r];
                if (actA) accoA[dt][r] *= alA[r];
            }

        // O += P V, both passes (shared Vs)
        __builtin_amdgcn_s_setprio(1);
#pragma unroll
        for (int c = 0; c < 2; ++c) {
            bf16x8 pa = *(const bf16x8*)&Ps[w][0][lm][c * 32 + g * 8];
#pragma unroll
            for (int dt = 0; dt < 8; ++dt) {
                bf16x8 bv = *(const bf16x8*)&Vs[dt * 16 + lm][c * 32 + g * 8];
                accoB[dt] = __builtin_amdgcn_mfma_f32_16x16x32_bf16(pa, bv, accoB[dt], 0, 0, 0);
            }
        }
        if (actA) {
#pragma unroll
            for (int c = 0; c < 2; ++c) {
                bf16x8 pa = *(const bf16x8*)&Ps[w][1][lm][c * 32 + g * 8];
#pragma unroll
                for (int dt = 0; dt < 8; ++dt) {
                    bf16x8 bv = *(const bf16x8*)&Vs[dt * 16 + lm][c * 32 + g * 8];
                    accoA[dt] = __builtin_amdgcn_mfma_f32_16x16x32_bf16(pa, bv, accoA[dt], 0, 0, 0);
                }
            }
        }
        __builtin_amdgcn_s_setprio(0);
    }
#undef ISSUE

    // epilogue: O /= l, bf16 out [SEQ][DIM], both passes
#pragma unroll
    for (int r = 0; r < 4; ++r) {
        float invlB = 1.0f / lrowB[r];
        float invlA = 1.0f / lrowA[r];
        size_t rowB = (size_t)(q0B + 16 * w + 4 * g + r) * DIM + h * HD;
        size_t rowA = (size_t)(q0A + 16 * w + 4 * g + r) * DIM + h * HD;
#pragma unroll
        for (int dt = 0; dt < 8; ++dt) {
            ao[rowB + dt * 16 + lm] = __float2bfloat16(accoB[dt][r] * invlB);
            ao[rowA + dt * 16 + lm] = __float2bfloat16(accoA[dt][r] * invlA);
        }
    }
}

// ---------------------------------------------------------------------------
// Workspace (exactly 48 MB, region-reused; stream order makes each safe):
//   [ 0,16) qb            (written by gemm_q, normed in place)
//   [16,20) kraw/kb       (gemm_kv, normed in place)
//   [20,22) Wkb  -> vt[20,24) after k_vt
//   [22,24) Wvb
//   [24,40) xb   -> ao    (xb dead after gemm_kv)
//   [40,48) Wqb  -> vraw[40,44) after gemm_q -> Wob[40,48) after k_vt
// ---------------------------------------------------------------------------
extern "C" void kernel_launch(void* const* d_in, const int* in_sizes, int n_in,
                              void* d_out, int out_size, void* d_ws, size_t ws_size,
                              hipStream_t stream) {
    const float* x  = (const float*)d_in[0];
    const float* Wq = (const float*)d_in[1];
    const float* Wk = (const float*)d_in[2];
    const float* Wv = (const float*)d_in[3];
    const float* Wo = (const float*)d_in[4];
    const float* qg = (const float*)d_in[5];
    float* out = (float*)d_out;

    char* ws = (char*)d_ws;
    const size_t MB = 1u << 20;
    bf16* qb   = (bf16*)(ws);
    bf16* kb   = (bf16*)(ws + 16 * MB);
    bf16* Wkb  = (bf16*)(ws + 20 * MB);
    bf16* Wvb  = (bf16*)(ws + 22 * MB);
    bf16* vt   = (bf16*)(ws + 20 * MB);
    bf16* xb   = (bf16*)(ws + 24 * MB);
    bf16* ao   = (bf16*)(ws + 24 * MB);
    bf16* Wqb  = (bf16*)(ws + 40 * MB);
    bf16* vraw = (bf16*)(ws + 40 * MB);
    bf16* Wob  = (bf16*)(ws + 40 * MB);

    k_cast8<<<4096, 256, 0, stream>>>(x,  xb,  1048576);
    k_cast8<<<2048, 256, 0, stream>>>(Wq, Wqb,  524288);
    k_cast8<<< 512, 256, 0, stream>>>(Wk, Wkb,  131072);
    k_cast8<<< 512, 256, 0, stream>>>(Wv, Wvb,  131072);
    k_gemm_q   <<<dim3(DIM / 128, SEQ / 128), 256, 0, stream>>>(xb, Wqb, qb);
    k_gemm_kv  <<<dim3(8, SEQ / 128),         256, 0, stream>>>(xb, Wkb, Wvb, kb, vraw);
    k_vt       <<<dim3(SEQ / 64, NKV),        256, 0, stream>>>(vraw, vt);
    k_cast8<<<2048, 256, 0, stream>>>(Wo, Wob,  524288);
    k_norm_rope<<<dim3(SEQ, NH + NKV),        128, 0, stream>>>(qb, kb, qg);
    k_attn_mfma<<<dim3(512),                  256, 0, stream>>>(qb, kb, vt, ao);
    k_gemm_o   <<<dim3(DIM / 128, SEQ / 128), 256, 0, stream>>>(ao, Wob, out);
}

// Round 9
// 450.408 us; speedup vs baseline: 9.3583x; 1.2833x over previous
//
#include <hip/hip_runtime.h>
#include <hip/hip_bf16.h>
#include <cmath>
#include <cfloat>

#define DIM   2048
#define SEQ   4096
#define NH    16
#define NKV   4
#define HD    128
#define KVD   512   // NKV*HD

typedef __bf16 bf16x8 __attribute__((ext_vector_type(8)));
typedef float  f32x4  __attribute__((ext_vector_type(4)));
using bf16 = __hip_bfloat16;

// ---------------------------------------------------------------------------
// async global->LDS, 16B per lane (m97/m104: dest wave-uniform, lane l -> +16l)
// ---------------------------------------------------------------------------
typedef __attribute__((address_space(1))) const unsigned int gu32;
typedef __attribute__((address_space(3))) unsigned int lu32;
__device__ __forceinline__ void gload_lds16(const bf16* g, bf16* l) {
    __builtin_amdgcn_global_load_lds((gu32*)g, (lu32*)l, 16, 0, 0);
}

// ---------------------------------------------------------------------------
// fp32 -> bf16 casts. k_cast4 fuses x,Wq,Wk,Wv (segmented by flat index).
// ---------------------------------------------------------------------------
__device__ __forceinline__ void cast8(const float* in, bf16* out, size_t o) {
    const float4* p = (const float4*)in + 2 * o;
    float4 a = p[0], b = p[1];
    bf16x8 v;
    v[0] = (__bf16)a.x; v[1] = (__bf16)a.y; v[2] = (__bf16)a.z; v[3] = (__bf16)a.w;
    v[4] = (__bf16)b.x; v[5] = (__bf16)b.y; v[6] = (__bf16)b.z; v[7] = (__bf16)b.w;
    *(bf16x8*)(out + 8 * o) = v;
}

__global__ __launch_bounds__(256) void k_cast4(const float* __restrict__ x,
                                               const float* __restrict__ Wq,
                                               const float* __restrict__ Wk,
                                               const float* __restrict__ Wv,
                                               bf16* __restrict__ xb,
                                               bf16* __restrict__ Wqb,
                                               bf16* __restrict__ Wkb,
                                               bf16* __restrict__ Wvb) {
    int i = blockIdx.x * 256 + threadIdx.x;          // 0 .. 1,835,007 (grid 7168)
    const float* in; bf16* out; int o;
    if (i < 1048576)      { in = x;  out = xb;  o = i; }
    else if (i < 1572864) { in = Wq; out = Wqb; o = i - 1048576; }
    else if (i < 1703936) { in = Wk; out = Wkb; o = i - 1572864; }
    else                  { in = Wv; out = Wvb; o = i - 1703936; }
    cast8(in, out, (size_t)o);
}

__global__ __launch_bounds__(256) void k_cast8(const float* __restrict__ in,
                                               bf16* __restrict__ out, int n8) {
    int i = blockIdx.x * 256 + threadIdx.x;
    if (i >= n8) return;
    cast8(in, out, (size_t)i);
}

// ---------------------------------------------------------------------------
// bf16 MFMA GEMM: C = A * B^T, m97 structure (128x128, BK=32, 4 waves).
// TRC: write C transposed [col][row] with row-stride SEQ (V^T fusion).
// ---------------------------------------------------------------------------
template <typename TC, bool TRC>
__device__ __forceinline__ void gemm_bf16_128(const bf16* __restrict__ A,
                                              const bf16* __restrict__ B,
                                              TC* __restrict__ C,
                                              int bm, int bn, int N, int K) {
    __shared__ __align__(16) bf16 As[128 * 32];
    __shared__ __align__(16) bf16 Bs[128 * 32];
    const int tid = threadIdx.x;
    const int l   = tid & 63;
    const int w   = tid >> 6;
    const int lm  = l & 15;
    const int g   = l >> 4;
    const int wr  = w >> 1;
    const int wc  = w & 1;
    const int rq  = l >> 2;
    const int kq  = (l & 3) * 8;

    f32x4 acc[4][4];
#pragma unroll
    for (int mi = 0; mi < 4; ++mi)
#pragma unroll
        for (int ni = 0; ni < 4; ++ni) {
            acc[mi][ni][0] = 0.f; acc[mi][ni][1] = 0.f;
            acc[mi][ni][2] = 0.f; acc[mi][ni][3] = 0.f;
        }

    const bf16* Ap0 = A + (size_t)(bm + w * 16 + rq) * K + kq;
    const bf16* Ap1 = Ap0 + (size_t)64 * K;
    const bf16* Bp0 = B + (size_t)(bn + w * 16 + rq) * K + kq;
    const bf16* Bp1 = Bp0 + (size_t)64 * K;
    bf16* lA0 = &As[w * 512];
    bf16* lA1 = &As[(w + 4) * 512];
    bf16* lB0 = &Bs[w * 512];
    bf16* lB1 = &Bs[(w + 4) * 512];

    for (int k0 = 0; k0 < K; k0 += 32) {
        gload_lds16(Ap0 + k0, lA0);
        gload_lds16(Ap1 + k0, lA1);
        gload_lds16(Bp0 + k0, lB0);
        gload_lds16(Bp1 + k0, lB1);
        __syncthreads();
        bf16x8 af[4], bfv[4];
#pragma unroll
        for (int mi = 0; mi < 4; ++mi)
            af[mi] = *(const bf16x8*)&As[(wr * 64 + mi * 16 + lm) * 32 + g * 8];
#pragma unroll
        for (int ni = 0; ni < 4; ++ni)
            bfv[ni] = *(const bf16x8*)&Bs[(wc * 64 + ni * 16 + lm) * 32 + g * 8];
#pragma unroll
        for (int mi = 0; mi < 4; ++mi)
#pragma unroll
            for (int ni = 0; ni < 4; ++ni)
                acc[mi][ni] = __builtin_amdgcn_mfma_f32_16x16x32_bf16(af[mi], bfv[ni], acc[mi][ni], 0, 0, 0);
        __syncthreads();
    }

#pragma unroll
    for (int mi = 0; mi < 4; ++mi)
#pragma unroll
        for (int rr = 0; rr < 4; ++rr) {
            int crow = bm + wr * 64 + mi * 16 + g * 4 + rr;
#pragma unroll
            for (int ni = 0; ni < 4; ++ni) {
                float vv = acc[mi][ni][rr];
                int col = bn + wc * 64 + ni * 16 + lm;
                if constexpr (TRC)                     C[(size_t)col * SEQ + crow] = __float2bfloat16(vv);
                else if constexpr (sizeof(TC) == 2)    C[(size_t)crow * N + col]   = __float2bfloat16(vv);
                else                                   C[(size_t)crow * N + col]   = vv;
            }
        }
}

// Fused Q/K/V projection; V written transposed into vt [KVD][SEQ].
__global__ __launch_bounds__(256) void k_gemm_qkv(const bf16* __restrict__ xb,
                                                  const bf16* __restrict__ Wqb,
                                                  const bf16* __restrict__ Wkb,
                                                  const bf16* __restrict__ Wvb,
                                                  bf16* __restrict__ qb,
                                                  bf16* __restrict__ kb,
                                                  bf16* __restrict__ vtp) {
    const int nbx = blockIdx.x;           // 0..23
    const int bm  = blockIdx.y * 128;
    if (nbx < 16)      gemm_bf16_128<bf16, false>(xb, Wqb, qb,  bm, nbx * 128,        DIM, DIM);
    else if (nbx < 20) gemm_bf16_128<bf16, false>(xb, Wkb, kb,  bm, (nbx - 16) * 128, KVD, DIM);
    else               gemm_bf16_128<bf16, true >(xb, Wvb, vtp, bm, (nbx - 20) * 128, KVD, DIM);
}

__global__ __launch_bounds__(256) void k_gemm_o(const bf16* __restrict__ ao,
                                                const bf16* __restrict__ Wob,
                                                float* __restrict__ out) {
    gemm_bf16_128<float, false>(ao, Wob, out, blockIdx.y * 128, blockIdx.x * 128, DIM, DIM);
}

// ---------------------------------------------------------------------------
// RMSNorm + RoPE (+ gain*scale for Q), bf16 in-place. grid (SEQ, NH+NKV).
// invf via exp2f (hw v_exp_f32); angle err <= ~7e-4 rad << bf16 rounding.
// ---------------------------------------------------------------------------
__global__ __launch_bounds__(128) void k_norm_rope(bf16* __restrict__ q,
                                                   bf16* __restrict__ k,
                                                   const float* __restrict__ qg) {
    const int t    = blockIdx.x;
    const int head = blockIdx.y;
    const int d    = threadIdx.x;

    bf16* base;
    float gain = 1.0f;
    if (head < NH) {
        base = q + (size_t)t * DIM + head * HD;
        gain = qg[head] * 0.08838834764831845f;   // fold softmax scale 128^-0.5
    } else {
        base = k + (size_t)t * KVD + (head - NH) * HD;
    }

    float xv = __bfloat162float(base[d]);
    float ss = xv * xv;
#pragma unroll
    for (int m = 1; m <= 32; m <<= 1) ss += __shfl_xor(ss, m, 64);

    __shared__ float red[2];
    __shared__ float sh[128];
    if ((d & 63) == 0) red[d >> 6] = ss;
    __syncthreads();
    float ms  = (red[0] + red[1]) * (1.0f / 128.0f);
    float inv = 1.0f / sqrtf(ms + 1.1920928955078125e-07f);
    sh[d] = xv * inv;
    __syncthreads();

    const int i = d & 63;
    float invf = exp2f((float)i * -0.20762050593046014f);  // 10000^(-i/64)
    float ang  = (float)t * invf;
    float cs   = cosf(ang);
    float sn   = sinf(ang);
    float x1   = sh[i];
    float x2   = sh[i + 64];
    float outv = (d < 64) ? (x1 * cs + x2 * sn) : (x2 * cs - x1 * sn);
    base[d] = __float2bfloat16(outv * gain);
}

// ---------------------------------------------------------------------------
// Online-softmax update for one pass (4 rows/lane-group of 16).
// ---------------------------------------------------------------------------
__device__ __forceinline__ void sm_pass(f32x4* accs, bool diag, int w, int g, int lm,
                                        float* mrow, float* lrow, float* alpha,
                                        bf16 (*PsW)[72]) {
#pragma unroll
    for (int r = 0; r < 4; ++r) {
        const int rrow = 16 * w + 4 * g + r;
        if (diag) {
#pragma unroll
            for (int nt = 0; nt < 4; ++nt)
                if (nt * 16 + lm > rrow) accs[nt][r] = -3e38f;
        }
        float mt = fmaxf(fmaxf(accs[0][r], accs[1][r]), fmaxf(accs[2][r], accs[3][r]));
#pragma unroll
        for (int mm = 1; mm <= 8; mm <<= 1) mt = fmaxf(mt, __shfl_xor(mt, mm, 64));
        float mnew = fmaxf(mrow[r], mt);
        float al   = __expf(mrow[r] - mnew);
        float rs   = 0.f;
#pragma unroll
        for (int nt = 0; nt < 4; ++nt) {
            float p = __expf(accs[nt][r] - mnew);
            accs[nt][r] = p;
            rs += p;
        }
#pragma unroll
        for (int mm = 1; mm <= 8; mm <<= 1) rs += __shfl_xor(rs, mm, 64);
        mrow[r]  = mnew;
        lrow[r]  = lrow[r] * al + rs;
        alpha[r] = al;
#pragma unroll
        for (int nt = 0; nt < 4; ++nt)
            PsW[4 * g + r][nt * 16 + lm] = __float2bfloat16(accs[nt][r]);
    }
}

// softmax + (skip-able) rescale + PV for one pass.
__device__ __forceinline__ void do_pass(f32x4* s, bool diag, int w, int g, int lm,
                                        float* mrow, float* lrow, f32x4* acco,
                                        bf16 (*PsW)[72], const bf16 (*Vp)[72]) {
    float alpha[4];
    sm_pass(s, diag, w, g, lm, mrow, lrow, alpha, PsW);
    // THR=0 defer: exp(0)==1 exactly when max didn't grow -> skip 128 mults.
    if (!__all((alpha[0] == 1.f) & (alpha[1] == 1.f) &
               (alpha[2] == 1.f) & (alpha[3] == 1.f))) {
#pragma unroll
        for (int dt = 0; dt < 8; ++dt)
#pragma unroll
            for (int r = 0; r < 4; ++r) acco[dt][r] *= alpha[r];
    }
    __builtin_amdgcn_s_setprio(1);
#pragma unroll
    for (int c = 0; c < 2; ++c) {
        bf16x8 pa = *(const bf16x8*)&PsW[lm][c * 32 + g * 8];
#pragma unroll
        for (int dt = 0; dt < 8; ++dt) {
            bf16x8 bv = *(const bf16x8*)&Vp[dt * 16 + lm][c * 32 + g * 8];
            acco[dt] = __builtin_amdgcn_mfma_f32_16x16x32_bf16(pa, bv, acco[dt], 0, 0, 0);
        }
    }
    __builtin_amdgcn_s_setprio(0);
}

// ---------------------------------------------------------------------------
// bf16 MFMA causal GQA flash attention: causal-paired (65 units/block, 512
// blocks = 2/CU) + single-barrier double-buffered K/V pipeline:
//   per tile: STAGE(p^1) | ISSUE(t+2) -> softmax+PV(t) -> barrier -> QK(t+1).
// LDS 80,896 B (2 blocks/CU). Passes serialized per wave (shared Ps buffer);
// overlap comes from 2 phase-shifted blocks/CU + PV||stage||issue ILP.
// ---------------------------------------------------------------------------
__global__ __launch_bounds__(256, 2) void k_attn_mfma(const bf16* __restrict__ qb,
                                                      const bf16* __restrict__ kb,
                                                      const bf16* __restrict__ vt,
                                                      bf16* __restrict__ ao) {
    __shared__ __align__(16) bf16 Ks[2][64][136];   // dbuf [kv][d] pad 8
    __shared__ __align__(16) bf16 Vs[2][128][72];   // dbuf [d][kv] pad 8
    __shared__ __align__(16) bf16 Ps[4][16][72];    // per-wave P (pass-shared)

    const int tid = threadIdx.x;
    const int l   = tid & 63;
    const int w   = tid >> 6;
    const int lm  = l & 15;
    const int g   = l >> 4;
    const int bid  = blockIdx.x;                   // 0..511
    const int orig = (bid & 7) * 64 + (bid >> 3);  // XCD-contiguous
    const int i    = orig & 31;
    const int h    = orig >> 5;
    const int kvh  = h >> 2;
    const int q0A  = i * 64;
    const int q0B  = (63 - i) * 64;

    bf16x8 qfA[4], qfB[4];
#pragma unroll
    for (int c = 0; c < 4; ++c) {
        qfA[c] = *(const bf16x8*)&qb[(size_t)(q0A + 16 * w + lm) * DIM + h * HD + c * 32 + g * 8];
        qfB[c] = *(const bf16x8*)&qb[(size_t)(q0B + 16 * w + lm) * DIM + h * HD + c * 32 + g * 8];
    }

    f32x4 accoA[8], accoB[8];
#pragma unroll
    for (int dt = 0; dt < 8; ++dt)
#pragma unroll
        for (int r = 0; r < 4; ++r) { accoA[dt][r] = 0.f; accoB[dt][r] = 0.f; }
    float mrowA[4] = {-3e38f, -3e38f, -3e38f, -3e38f};
    float mrowB[4] = {-3e38f, -3e38f, -3e38f, -3e38f};
    float lrowA[4] = {0.f, 0.f, 0.f, 0.f};
    float lrowB[4] = {0.f, 0.f, 0.f, 0.f};

    bf16x8 kreg[4], vreg[4];
#define ISSUE(KV0)                                                              \
    do {                                                                        \
        _Pragma("unroll") for (int it = 0; it < 4; ++it) {                      \
            int idx = tid + it * 256;                                           \
            int r = idx >> 4, d0 = (idx & 15) * 8;                              \
            kreg[it] = *(const bf16x8*)&kb[(size_t)((KV0) + r) * KVD + kvh * HD + d0]; \
        }                                                                       \
        _Pragma("unroll") for (int it = 0; it < 4; ++it) {                      \
            int idx = tid + it * 256;                                           \
            int d = idx >> 3, tt = (idx & 7) * 8;                               \
            vreg[it] = *(const bf16x8*)&vt[(size_t)(kvh * HD + d) * SEQ + (KV0) + tt]; \
        }                                                                       \
    } while (0)

#define STAGE(PN)                                                               \
    do {                                                                        \
        _Pragma("unroll") for (int it = 0; it < 4; ++it) {                      \
            int idx = tid + it * 256;                                           \
            *(bf16x8*)&Ks[PN][idx >> 4][(idx & 15) * 8] = kreg[it];             \
        }                                                                       \
        _Pragma("unroll") for (int it = 0; it < 4; ++it) {                      \
            int idx = tid + it * 256;                                           \
            *(bf16x8*)&Vs[PN][idx >> 3][(idx & 7) * 8] = vreg[it];              \
        }                                                                       \
    } while (0)

#define QKT(S, QF, PN)                                                          \
    do {                                                                        \
        _Pragma("unroll") for (int nt = 0; nt < 4; ++nt) {                      \
            S[nt][0] = 0.f; S[nt][1] = 0.f; S[nt][2] = 0.f; S[nt][3] = 0.f; }   \
        __builtin_amdgcn_s_setprio(1);                                          \
        _Pragma("unroll") for (int c = 0; c < 4; ++c)                           \
        _Pragma("unroll") for (int nt = 0; nt < 4; ++nt) {                      \
            bf16x8 bk = *(const bf16x8*)&Ks[PN][nt * 16 + lm][c * 32 + g * 8];  \
            S[nt] = __builtin_amdgcn_mfma_f32_16x16x32_bf16(QF[c], bk, S[nt], 0, 0, 0); \
        }                                                                       \
        __builtin_amdgcn_s_setprio(0);                                          \
    } while (0)

    const int ntiles = 64 - i;                     // >= 33

    // prologue: tile 0 staged, tile 1 in regs, QK(0) issued
    ISSUE(0);
    STAGE(0);
    ISSUE(64);
    __syncthreads();
    f32x4 sB[4], sA[4];
    QKT(sB, qfB, 0);
    QKT(sA, qfA, 0);
    int p = 0;

    for (int t = 0; t < ntiles; ++t) {
        const bool last = (t + 1 == ntiles);
        if (!last) {
            STAGE(p ^ 1);                          // write next tile (other buf)
            if (t + 2 < ntiles) ISSUE((t + 2) * 64);
        }
        do_pass(sB, t == ntiles - 1, w, g, lm, mrowB, lrowB, accoB, Ps[w], Vs[p]);
        if (t <= i)
            do_pass(sA, t == i, w, g, lm, mrowA, lrowA, accoA, Ps[w], Vs[p]);
        if (!last) {
            __syncthreads();                       // next tile visible everywhere
            QKT(sB, qfB, p ^ 1);
            if (t + 1 <= i) QKT(sA, qfA, p ^ 1);
            p ^= 1;
        }
    }
#undef ISSUE
#undef STAGE
#undef QKT

    // epilogue: O /= l, bf16 out [SEQ][DIM], both passes
#pragma unroll
    for (int r = 0; r < 4; ++r) {
        float invlB = 1.0f / lrowB[r];
        float invlA = 1.0f / lrowA[r];
        size_t rowB = (size_t)(q0B + 16 * w + 4 * g + r) * DIM + h * HD;
        size_t rowA = (size_t)(q0A + 16 * w + 4 * g + r) * DIM + h * HD;
#pragma unroll
        for (int dt = 0; dt < 8; ++dt) {
            ao[rowB + dt * 16 + lm] = __float2bfloat16(accoB[dt][r] * invlB);
            ao[rowA + dt * 16 + lm] = __float2bfloat16(accoA[dt][r] * invlA);
        }
    }
}

// ---------------------------------------------------------------------------
// Workspace (36 MB of d_ws; qb borrows d_out until gemm_o):
//   ws [ 0,16) xb   -> ao after QKV gemm (xb dead)
//   ws [16,24) Wqb  -> Wob after QKV gemm (Wqb dead)
//   ws [24,26) Wkb | [26,28) Wvb | [28,32) kb | [32,36) vt
//   d_out [0,16MB) qb (bf16) -- dead before gemm_o overwrites d_out w/ fp32.
// ---------------------------------------------------------------------------
extern "C" void kernel_launch(void* const* d_in, const int* in_sizes, int n_in,
                              void* d_out, int out_size, void* d_ws, size_t ws_size,
                              hipStream_t stream) {
    const float* x  = (const float*)d_in[0];
    const float* Wq = (const float*)d_in[1];
    const float* Wk = (const float*)d_in[2];
    const float* Wv = (const float*)d_in[3];
    const float* Wo = (const float*)d_in[4];
    const float* qg = (const float*)d_in[5];

    char* ws = (char*)d_ws;
    const size_t MB = 1u << 20;
    bf16* xb  = (bf16*)(ws);
    bf16* ao  = (bf16*)(ws);
    bf16* Wqb = (bf16*)(ws + 16 * MB);
    bf16* Wob = (bf16*)(ws + 16 * MB);
    bf16* Wkb = (bf16*)(ws + 24 * MB);
    bf16* Wvb = (bf16*)(ws + 26 * MB);
    bf16* kb  = (bf16*)(ws + 28 * MB);
    bf16* vt  = (bf16*)(ws + 32 * MB);
    bf16* qb  = (bf16*)d_out;

    k_cast4    <<<7168, 256, 0, stream>>>(x, Wq, Wk, Wv, xb, Wqb, Wkb, Wvb);
    k_gemm_qkv <<<dim3(24, SEQ / 128), 256, 0, stream>>>(xb, Wqb, Wkb, Wvb, qb, kb, vt);
    k_cast8    <<<2048, 256, 0, stream>>>(Wo, Wob, 524288);
    k_norm_rope<<<dim3(SEQ, NH + NKV), 128, 0, stream>>>(qb, kb, qg);
    k_attn_mfma<<<dim3(512), 256, 0, stream>>>(qb, kb, vt, ao);
    k_gemm_o   <<<dim3(DIM / 128, SEQ / 128), 256, 0, stream>>>(ao, Wob, (float*)d_out);
}